// Round 4
// baseline (89.088 us; speedup 1.0000x reference)
//
#include <hip/hip_runtime.h>

#define NC 256
#define NB 32
#define HW 4096
#define HW4 1024
#define KC 768   // KERNEL * NC
#define BN_EPS 1e-5f
#define CG 16    // channels per apply block

typedef float f32x4 __attribute__((ext_vector_type(4)));

// ---------------- Kernel 1: global average pool per (b,c) ----------------
__global__ __launch_bounds__(256) void gap_kernel(const float* __restrict__ x,
                                                  float* __restrict__ g) {
    const int bc = blockIdx.x;
    const f32x4* xp = reinterpret_cast<const f32x4*>(x) + (size_t)bc * HW4;
    const int t = threadIdx.x;
    float s = 0.f;
#pragma unroll
    for (int k = 0; k < 4; ++k) {
        f32x4 v = xp[t + k * 256];
        s += (v.x + v.y) + (v.z + v.w);
    }
#pragma unroll
    for (int off = 32; off > 0; off >>= 1) s += __shfl_down(s, off, 64);
    __shared__ float warp_sums[4];
    const int lane = t & 63, w = t >> 6;
    if (lane == 0) warp_sums[w] = s;
    __syncthreads();
    if (t == 0) {
        float tot = (warp_sums[0] + warp_sums[1]) + (warp_sums[2] + warp_sums[3]);
        g[bc] = tot * (1.0f / HW);
    }
}

// ---------------- Kernel 2: 1x1 conv (768x256 dot) + BN + tanh ----------------
__global__ __launch_bounds__(256) void filt_kernel(const float* __restrict__ g,
                                                   const float* __restrict__ cw,
                                                   const float* __restrict__ bn_w,
                                                   const float* __restrict__ bn_b,
                                                   const float* __restrict__ bn_m,
                                                   const float* __restrict__ bn_v,
                                                   float* __restrict__ f) {
    const int b = blockIdx.y;
    const int t = threadIdx.x;
    __shared__ float gs[NC];
    gs[t] = g[b * NC + t];
    __syncthreads();
    const int wave = t >> 6, lane = t & 63;
    const f32x4 gv = reinterpret_cast<const f32x4*>(gs)[lane];
    const int row0 = blockIdx.x * 128 + wave * 32;
#pragma unroll 4
    for (int i = 0; i < 32; ++i) {
        const int j = row0 + i;
        const f32x4 wv = reinterpret_cast<const f32x4*>(cw + (size_t)j * NC)[lane];
        float s = fmaf(gv.x, wv.x, fmaf(gv.y, wv.y, fmaf(gv.z, wv.z, gv.w * wv.w)));
#pragma unroll
        for (int off = 32; off > 0; off >>= 1) s += __shfl_down(s, off, 64);
        if (lane == 0) {
            float yn = (s - bn_m[j]) * rsqrtf(bn_v[j] + BN_EPS) * bn_w[j] + bn_b[j];
            f[b * KC + j] = tanhf(yn);
        }
    }
}

// ---------------- Kernel 3: dynamic channel-local filter + affine ----------------
// Block owns (b, CG-channel group, 256-float4 hw chunk). Sliding 3-plane
// register window along c. 2048 blocks -> 32 waves/CU for latency hiding.
__global__ __launch_bounds__(256) void apply_kernel(const float* __restrict__ x,
                                                    const float* __restrict__ f,
                                                    const float* __restrict__ gamma,
                                                    const float* __restrict__ beta,
                                                    float* __restrict__ out) {
    const int bid = blockIdx.x;          // 2048 blocks
    const int hwt = bid & 3;
    const int cg  = (bid >> 2) & 15;
    const int b   = bid >> 6;
    const int t = threadIdx.x;
    const int hw = hwt * 256 + t;        // float4 index within plane
    const int c0 = cg * CG;

    const f32x4* x4 = reinterpret_cast<const f32x4*>(x) + (size_t)b * NC * HW4 + hw;
    f32x4* o4 = reinterpret_cast<f32x4*>(out) + (size_t)b * NC * HW4 + hw;
    const float* fb = f + b * KC;

    f32x4 cur = x4[(size_t)c0 * HW4];
    f32x4 nxt = x4[(size_t)(c0 + 1) * HW4];
    f32x4 prv = (c0 == 0) ? nxt : x4[(size_t)(c0 - 1) * HW4];

#pragma unroll 4
    for (int ci = 0; ci < CG; ++ci) {
        const int c = c0 + ci;
        const int cn = (c + 2 < NC) ? (c + 2) : (NC - 1);
        f32x4 nn = x4[(size_t)cn * HW4];          // prefetch for next iter
        const float f0 = fb[c];
        const float f1 = fb[NC + c];
        const float f2 = fb[2 * NC + c];
        const float ga = gamma[c];
        const float be = beta[c];
        const f32x4 xm = (c == 0) ? nxt : prv;        // reflect left edge
        const f32x4 xq = (c == NC - 1) ? prv : nxt;   // reflect right edge
        f32x4 r;
        r.x = fmaf(fmaf(f0, xm.x, fmaf(f1, cur.x, f2 * xq.x)), ga, cur.x * be);
        r.y = fmaf(fmaf(f0, xm.y, fmaf(f1, cur.y, f2 * xq.y)), ga, cur.y * be);
        r.z = fmaf(fmaf(f0, xm.z, fmaf(f1, cur.z, f2 * xq.z)), ga, cur.z * be);
        r.w = fmaf(fmaf(f0, xm.w, fmaf(f1, cur.w, f2 * xq.w)), ga, cur.w * be);
        __builtin_nontemporal_store(r, &o4[(size_t)c * HW4]);
        prv = cur; cur = nxt; nxt = nn;
    }
}

extern "C" void kernel_launch(void* const* d_in, const int* in_sizes, int n_in,
                              void* d_out, int out_size, void* d_ws, size_t ws_size,
                              hipStream_t stream) {
    const float* x     = (const float*)d_in[0];
    const float* cw    = (const float*)d_in[1];
    const float* bn_w  = (const float*)d_in[2];
    const float* bn_b  = (const float*)d_in[3];
    const float* bn_m  = (const float*)d_in[4];
    const float* bn_v  = (const float*)d_in[5];
    const float* gamma = (const float*)d_in[6];
    const float* beta  = (const float*)d_in[7];
    float* out = (float*)d_out;

    float* g = (float*)d_ws;                    // NB*NC floats
    float* f = g + NB * NC;                     // NB*KC floats

    gap_kernel<<<NB * NC, 256, 0, stream>>>(x, g);
    filt_kernel<<<dim3(6, NB), 256, 0, stream>>>(g, cw, bn_w, bn_b, bn_m, bn_v, f);
    apply_kernel<<<NB * (NC / CG) * 4, 256, 0, stream>>>(x, f, gamma, beta, out);
}

// Round 6
// 77.424 us; speedup vs baseline: 1.1506x; 1.1506x over previous
//
#include <hip/hip_runtime.h>

#define NC 256
#define NB 32
#define HW 4096
#define HW4 1024
#define KC 768   // KERNEL * NC
#define BN_EPS 1e-5f

typedef float f32x4 __attribute__((ext_vector_type(4)));

// ---------------- Kernel 1: global average pool per (b,c) ----------------
__global__ __launch_bounds__(256) void gap_kernel(const float* __restrict__ x,
                                                  float* __restrict__ g) {
    const int bc = blockIdx.x;
    const f32x4* xp = reinterpret_cast<const f32x4*>(x) + (size_t)bc * HW4;
    const int t = threadIdx.x;
    float s = 0.f;
#pragma unroll
    for (int k = 0; k < 4; ++k) {
        f32x4 v = xp[t + k * 256];
        s += (v.x + v.y) + (v.z + v.w);
    }
#pragma unroll
    for (int off = 32; off > 0; off >>= 1) s += __shfl_down(s, off, 64);
    __shared__ float warp_sums[4];
    const int lane = t & 63, w = t >> 6;
    if (lane == 0) warp_sums[w] = s;
    __syncthreads();
    if (t == 0) {
        float tot = (warp_sums[0] + warp_sums[1]) + (warp_sums[2] + warp_sums[3]);
        g[bc] = tot * (1.0f / HW);
    }
}

// ---------------- Kernel 2: 1x1 conv (768x256 dot) + BN + tanh ----------------
// grid (24, 32): blockIdx.y = batch, 32 rows/block, 8 rows/wave.
__global__ __launch_bounds__(256) void filt_kernel(const float* __restrict__ g,
                                                   const float* __restrict__ cw,
                                                   const float* __restrict__ bn_w,
                                                   const float* __restrict__ bn_b,
                                                   const float* __restrict__ bn_m,
                                                   const float* __restrict__ bn_v,
                                                   float* __restrict__ f) {
    const int b = blockIdx.y;
    const int t = threadIdx.x;
    __shared__ float gs[NC];
    gs[t] = g[b * NC + t];
    __syncthreads();
    const int wave = t >> 6, lane = t & 63;
    const f32x4 gv = reinterpret_cast<const f32x4*>(gs)[lane];
    const int row0 = blockIdx.x * 32 + wave * 8;
#pragma unroll
    for (int i = 0; i < 8; ++i) {
        const int j = row0 + i;
        const f32x4 wv = reinterpret_cast<const f32x4*>(cw + (size_t)j * NC)[lane];
        float s = fmaf(gv.x, wv.x, fmaf(gv.y, wv.y, fmaf(gv.z, wv.z, gv.w * wv.w)));
#pragma unroll
        for (int off = 32; off > 0; off >>= 1) s += __shfl_down(s, off, 64);
        if (lane == 0) {
            float yn = (s - bn_m[j]) * rsqrtf(bn_v[j] + BN_EPS) * bn_w[j] + bn_b[j];
            f[b * KC + j] = tanhf(yn);
        }
    }
}

// ---------------- Kernel 3: dynamic channel-local filter + affine ----------------
// Block owns (b, 64-channel group, 256-float4 hw chunk). Sliding 3-plane
// register window along c: each x element loaded ONCE. PLAIN stores this
// round (A/B vs nt: harness fills sustain 7 TB/s with cached stores).
__global__ __launch_bounds__(256) void apply_kernel(const float* __restrict__ x,
                                                    const float* __restrict__ f,
                                                    const float* __restrict__ gamma,
                                                    const float* __restrict__ beta,
                                                    float* __restrict__ out) {
    const int bid = blockIdx.x;          // 512 blocks
    const int b   = bid >> 4;
    const int cg  = (bid >> 2) & 3;
    const int hwt = bid & 3;
    const int t = threadIdx.x;
    const int hw = hwt * 256 + t;        // float4 index within plane
    const int c0 = cg * 64;

    const f32x4* x4 = reinterpret_cast<const f32x4*>(x) + (size_t)b * NC * HW4 + hw;
    f32x4* o4 = reinterpret_cast<f32x4*>(out) + (size_t)b * NC * HW4 + hw;
    const float* fb = f + b * KC;

    f32x4 cur = x4[(size_t)c0 * HW4];
    f32x4 nxt = x4[(size_t)(c0 + 1) * HW4];
    f32x4 prv = (c0 == 0) ? nxt : x4[(size_t)(c0 - 1) * HW4];

#pragma unroll 4
    for (int ci = 0; ci < 64; ++ci) {
        const int c = c0 + ci;
        const int cn = (c + 2 < NC) ? (c + 2) : (NC - 1);
        f32x4 nn = x4[(size_t)cn * HW4];          // prefetch for next iter
        const float f0 = fb[c];
        const float f1 = fb[NC + c];
        const float f2 = fb[2 * NC + c];
        const float ga = gamma[c];
        const float be = beta[c];
        const f32x4 xm = (c == 0) ? nxt : prv;        // reflect left edge
        const f32x4 xq = (c == NC - 1) ? prv : nxt;   // reflect right edge
        f32x4 r;
        r.x = fmaf(fmaf(f0, xm.x, fmaf(f1, cur.x, f2 * xq.x)), ga, cur.x * be);
        r.y = fmaf(fmaf(f0, xm.y, fmaf(f1, cur.y, f2 * xq.y)), ga, cur.y * be);
        r.z = fmaf(fmaf(f0, xm.z, fmaf(f1, cur.z, f2 * xq.z)), ga, cur.z * be);
        r.w = fmaf(fmaf(f0, xm.w, fmaf(f1, cur.w, f2 * xq.w)), ga, cur.w * be);
        o4[(size_t)c * HW4] = r;                      // plain cached store
        prv = cur; cur = nxt; nxt = nn;
    }
}

extern "C" void kernel_launch(void* const* d_in, const int* in_sizes, int n_in,
                              void* d_out, int out_size, void* d_ws, size_t ws_size,
                              hipStream_t stream) {
    const float* x     = (const float*)d_in[0];
    const float* cw    = (const float*)d_in[1];
    const float* bn_w  = (const float*)d_in[2];
    const float* bn_b  = (const float*)d_in[3];
    const float* bn_m  = (const float*)d_in[4];
    const float* bn_v  = (const float*)d_in[5];
    const float* gamma = (const float*)d_in[6];
    const float* beta  = (const float*)d_in[7];
    float* out = (float*)d_out;

    float* g = (float*)d_ws;                    // NB*NC floats
    float* f = g + NB * NC;                     // NB*KC floats

    gap_kernel<<<NB * NC, 256, 0, stream>>>(x, g);
    filt_kernel<<<dim3(24, NB), 256, 0, stream>>>(g, cw, bn_w, bn_b, bn_m, bn_v, f);
    apply_kernel<<<512, 256, 0, stream>>>(x, f, gamma, beta, out);
}

// Round 7
// 76.357 us; speedup vs baseline: 1.1667x; 1.0140x over previous
//
#include <hip/hip_runtime.h>

#define NC 256
#define NB 32
#define HW 4096
#define HW4 1024
#define KC 768   // KERNEL * NC
#define BN_EPS 1e-5f

typedef float f32x4 __attribute__((ext_vector_type(4)));

// ---------------- Kernel 1: global average pool per (b,c) ----------------
__global__ __launch_bounds__(256) void gap_kernel(const float* __restrict__ x,
                                                  float* __restrict__ g) {
    const int bc = blockIdx.x;
    const f32x4* xp = reinterpret_cast<const f32x4*>(x) + (size_t)bc * HW4;
    const int t = threadIdx.x;
    float s = 0.f;
#pragma unroll
    for (int k = 0; k < 4; ++k) {
        f32x4 v = xp[t + k * 256];
        s += (v.x + v.y) + (v.z + v.w);
    }
#pragma unroll
    for (int off = 32; off > 0; off >>= 1) s += __shfl_down(s, off, 64);
    __shared__ float warp_sums[4];
    const int lane = t & 63, w = t >> 6;
    if (lane == 0) warp_sums[w] = s;
    __syncthreads();
    if (t == 0) {
        float tot = (warp_sums[0] + warp_sums[1]) + (warp_sums[2] + warp_sums[3]);
        g[bc] = tot * (1.0f / HW);
    }
}

// ---------------- Kernel 2: 1x1 conv (768x256 dot) + BN + tanh ----------------
__global__ __launch_bounds__(256) void filt_kernel(const float* __restrict__ g,
                                                   const float* __restrict__ cw,
                                                   const float* __restrict__ bn_w,
                                                   const float* __restrict__ bn_b,
                                                   const float* __restrict__ bn_m,
                                                   const float* __restrict__ bn_v,
                                                   float* __restrict__ f) {
    const int b = blockIdx.y;
    const int t = threadIdx.x;
    __shared__ float gs[NC];
    gs[t] = g[b * NC + t];
    __syncthreads();
    const int wave = t >> 6, lane = t & 63;
    const f32x4 gv = reinterpret_cast<const f32x4*>(gs)[lane];
    const int row0 = blockIdx.x * 32 + wave * 8;
#pragma unroll
    for (int i = 0; i < 8; ++i) {
        const int j = row0 + i;
        const f32x4 wv = reinterpret_cast<const f32x4*>(cw + (size_t)j * NC)[lane];
        float s = fmaf(gv.x, wv.x, fmaf(gv.y, wv.y, fmaf(gv.z, wv.z, gv.w * wv.w)));
#pragma unroll
        for (int off = 32; off > 0; off >>= 1) s += __shfl_down(s, off, 64);
        if (lane == 0) {
            float yn = (s - bn_m[j]) * rsqrtf(bn_v[j] + BN_EPS) * bn_w[j] + bn_b[j];
            f[b * KC + j] = tanhf(yn);
        }
    }
}

// ---------------- Kernel 3: dynamic channel-local filter + affine ----------------
// Block owns (b, 64-channel group, 256-float4 hw chunk). Sliding 3-plane
// register window along c, PREFETCH DEPTH 2 (two planes in flight/thread ->
// ~16KB/CU outstanding at 512 blocks). Coefs staged once in LDS.
__global__ __launch_bounds__(256) void apply_kernel(const float* __restrict__ x,
                                                    const float* __restrict__ f,
                                                    const float* __restrict__ gamma,
                                                    const float* __restrict__ beta,
                                                    float* __restrict__ out) {
    const int bid = blockIdx.x;          // 512 blocks
    const int b   = bid >> 4;
    const int cg  = (bid >> 2) & 3;
    const int hwt = bid & 3;
    const int t = threadIdx.x;
    const int hw = hwt * 256 + t;        // float4 index within plane
    const int c0 = cg * 64;

    // stage per-channel coefficients in LDS (one pass, then broadcast reads)
    __shared__ float f_s[3][64];
    __shared__ float ga_s[64], be_s[64];
    {
        const float* fb = f + b * KC;
        if (t < 192) f_s[t >> 6][t & 63] = fb[(t >> 6) * NC + c0 + (t & 63)];
        else         ga_s[t - 192] = gamma[c0 + t - 192];
        if (t < 64)  be_s[t] = beta[c0 + t];
    }

    const f32x4* x4 = reinterpret_cast<const f32x4*>(x) + (size_t)b * NC * HW4 + hw;
    f32x4* o4 = reinterpret_cast<f32x4*>(out) + (size_t)b * NC * HW4 + hw;

    // 5-deep plane pipeline: prv,cur,nxt active; p2,p3 in flight
    f32x4 cur = x4[(size_t)c0 * HW4];
    f32x4 nxt = x4[(size_t)(c0 + 1) * HW4];
    f32x4 p2  = x4[(size_t)(c0 + 2) * HW4];
    f32x4 p3  = x4[(size_t)(c0 + 3) * HW4];
    f32x4 prv = (c0 == 0) ? nxt : x4[(size_t)(c0 - 1) * HW4];

    __syncthreads();

#pragma unroll 4
    for (int ci = 0; ci < 64; ++ci) {
        const int c = c0 + ci;
        const int cn = (c + 4 < NC) ? (c + 4) : (NC - 1);   // clamped prefetch
        f32x4 nn = x4[(size_t)cn * HW4];
        const float f0 = f_s[0][ci];
        const float f1 = f_s[1][ci];
        const float f2 = f_s[2][ci];
        const float ga = ga_s[ci];
        const float be = be_s[ci];
        const f32x4 xm = (c == 0) ? nxt : prv;        // reflect left edge
        const f32x4 xq = (c == NC - 1) ? prv : nxt;   // reflect right edge
        f32x4 r;
        r.x = fmaf(fmaf(f0, xm.x, fmaf(f1, cur.x, f2 * xq.x)), ga, cur.x * be);
        r.y = fmaf(fmaf(f0, xm.y, fmaf(f1, cur.y, f2 * xq.y)), ga, cur.y * be);
        r.z = fmaf(fmaf(f0, xm.z, fmaf(f1, cur.z, f2 * xq.z)), ga, cur.z * be);
        r.w = fmaf(fmaf(f0, xm.w, fmaf(f1, cur.w, f2 * xq.w)), ga, cur.w * be);
        o4[(size_t)c * HW4] = r;
        prv = cur; cur = nxt; nxt = p2; p2 = p3; p3 = nn;
    }
}

extern "C" void kernel_launch(void* const* d_in, const int* in_sizes, int n_in,
                              void* d_out, int out_size, void* d_ws, size_t ws_size,
                              hipStream_t stream) {
    const float* x     = (const float*)d_in[0];
    const float* cw    = (const float*)d_in[1];
    const float* bn_w  = (const float*)d_in[2];
    const float* bn_b  = (const float*)d_in[3];
    const float* bn_m  = (const float*)d_in[4];
    const float* bn_v  = (const float*)d_in[5];
    const float* gamma = (const float*)d_in[6];
    const float* beta  = (const float*)d_in[7];
    float* out = (float*)d_out;

    float* g = (float*)d_ws;                    // NB*NC floats
    float* f = g + NB * NC;                     // NB*KC floats

    gap_kernel<<<NB * NC, 256, 0, stream>>>(x, g);
    filt_kernel<<<dim3(24, NB), 256, 0, stream>>>(g, cw, bn_w, bn_b, bn_m, bn_v, f);
    apply_kernel<<<512, 256, 0, stream>>>(x, f, gamma, beta, out);
}

// Round 8
// 75.127 us; speedup vs baseline: 1.1858x; 1.0164x over previous
//
#include <hip/hip_runtime.h>

#define NC 256
#define NB 32
#define HW 4096
#define HW4 1024
#define KC 768   // KERNEL * NC
#define BN_EPS 1e-5f
#define CG 32    // channels per apply block

typedef float f32x4 __attribute__((ext_vector_type(4)));

// ---------------- Kernel 1: global average pool per (b,c) ----------------
__global__ __launch_bounds__(256) void gap_kernel(const float* __restrict__ x,
                                                  float* __restrict__ g) {
    const int bc = blockIdx.x;
    const f32x4* xp = reinterpret_cast<const f32x4*>(x) + (size_t)bc * HW4;
    const int t = threadIdx.x;
    float s = 0.f;
#pragma unroll
    for (int k = 0; k < 4; ++k) {
        f32x4 v = xp[t + k * 256];
        s += (v.x + v.y) + (v.z + v.w);
    }
#pragma unroll
    for (int off = 32; off > 0; off >>= 1) s += __shfl_down(s, off, 64);
    __shared__ float warp_sums[4];
    const int lane = t & 63, w = t >> 6;
    if (lane == 0) warp_sums[w] = s;
    __syncthreads();
    if (t == 0) {
        float tot = (warp_sums[0] + warp_sums[1]) + (warp_sums[2] + warp_sums[3]);
        g[bc] = tot * (1.0f / HW);
    }
}

// ---------------- Kernel 2: 1x1 conv (768x256 dot) + BN + tanh ----------------
__global__ __launch_bounds__(256) void filt_kernel(const float* __restrict__ g,
                                                   const float* __restrict__ cw,
                                                   const float* __restrict__ bn_w,
                                                   const float* __restrict__ bn_b,
                                                   const float* __restrict__ bn_m,
                                                   const float* __restrict__ bn_v,
                                                   float* __restrict__ f) {
    const int b = blockIdx.y;
    const int t = threadIdx.x;
    __shared__ float gs[NC];
    gs[t] = g[b * NC + t];
    __syncthreads();
    const int wave = t >> 6, lane = t & 63;
    const f32x4 gv = reinterpret_cast<const f32x4*>(gs)[lane];
    const int row0 = blockIdx.x * 32 + wave * 8;
#pragma unroll
    for (int i = 0; i < 8; ++i) {
        const int j = row0 + i;
        const f32x4 wv = reinterpret_cast<const f32x4*>(cw + (size_t)j * NC)[lane];
        float s = fmaf(gv.x, wv.x, fmaf(gv.y, wv.y, fmaf(gv.z, wv.z, gv.w * wv.w)));
#pragma unroll
        for (int off = 32; off > 0; off >>= 1) s += __shfl_down(s, off, 64);
        if (lane == 0) {
            float yn = (s - bn_m[j]) * rsqrtf(bn_v[j] + BN_EPS) * bn_w[j] + bn_b[j];
            f[b * KC + j] = tanhf(yn);
        }
    }
}

// ---------------- Kernel 3: dynamic channel-local filter + affine ----------------
// Block = (b, 32-channel group), owns the FULL 16KB plane per channel step:
// 256 threads x 4 f32x4. Streams are 16KB-linear per channel (read and write),
// matching the shape of the 7.15 TB/s fill pattern. 256 blocks, halo +6.25%.
__global__ __launch_bounds__(256) void apply_kernel(const float* __restrict__ x,
                                                    const float* __restrict__ f,
                                                    const float* __restrict__ gamma,
                                                    const float* __restrict__ beta,
                                                    float* __restrict__ out) {
    const int bid = blockIdx.x;          // 256 blocks
    const int cgp = bid & 7;
    const int b   = bid >> 3;
    const int t   = threadIdx.x;
    const int c0  = cgp * CG;

    __shared__ float f_s[3][CG];
    __shared__ float ga_s[CG], be_s[CG];
    {
        const float* fb = f + b * KC;
        if (t < 96)       f_s[t >> 5][t & 31] = fb[(t >> 5) * NC + c0 + (t & 31)];
        else if (t < 128) ga_s[t & 31] = gamma[c0 + (t & 31)];
        else if (t < 160) be_s[t & 31] = beta[c0 + (t & 31)];
    }

    const size_t bbase = (size_t)b * NC * HW4;
    const f32x4* x4 = reinterpret_cast<const f32x4*>(x) + bbase;
    f32x4* o4 = reinterpret_cast<f32x4*>(out) + bbase;

    f32x4 prv[4], cur[4], nxt[4];
#pragma unroll
    for (int j = 0; j < 4; ++j) cur[j] = x4[(size_t)c0 * HW4 + t + j * 256];
#pragma unroll
    for (int j = 0; j < 4; ++j) nxt[j] = x4[(size_t)(c0 + 1) * HW4 + t + j * 256];
    if (c0 == 0) {
#pragma unroll
        for (int j = 0; j < 4; ++j) prv[j] = nxt[j];
    } else {
#pragma unroll
        for (int j = 0; j < 4; ++j) prv[j] = x4[(size_t)(c0 - 1) * HW4 + t + j * 256];
    }
    __syncthreads();

#pragma unroll 2
    for (int ci = 0; ci < CG; ++ci) {
        const int c  = c0 + ci;
        const int cn = (c + 2 < NC) ? (c + 2) : (NC - 1);   // clamped prefetch
        f32x4 nn[4];
#pragma unroll
        for (int j = 0; j < 4; ++j) nn[j] = x4[(size_t)cn * HW4 + t + j * 256];
        const float f0 = f_s[0][ci];
        const float f1 = f_s[1][ci];
        const float f2 = f_s[2][ci];
        const float ga = ga_s[ci];
        const float be = be_s[ci];
#pragma unroll
        for (int j = 0; j < 4; ++j) {
            const f32x4 xm = (c == 0) ? nxt[j] : prv[j];        // reflect left
            const f32x4 xq = (c == NC - 1) ? prv[j] : nxt[j];   // reflect right
            const f32x4 xc = cur[j];
            f32x4 r;
            r.x = fmaf(fmaf(f0, xm.x, fmaf(f1, xc.x, f2 * xq.x)), ga, xc.x * be);
            r.y = fmaf(fmaf(f0, xm.y, fmaf(f1, xc.y, f2 * xq.y)), ga, xc.y * be);
            r.z = fmaf(fmaf(f0, xm.z, fmaf(f1, xc.z, f2 * xq.z)), ga, xc.z * be);
            r.w = fmaf(fmaf(f0, xm.w, fmaf(f1, xc.w, f2 * xq.w)), ga, xc.w * be);
            o4[(size_t)c * HW4 + t + j * 256] = r;
        }
#pragma unroll
        for (int j = 0; j < 4; ++j) { prv[j] = cur[j]; cur[j] = nxt[j]; nxt[j] = nn[j]; }
    }
}

extern "C" void kernel_launch(void* const* d_in, const int* in_sizes, int n_in,
                              void* d_out, int out_size, void* d_ws, size_t ws_size,
                              hipStream_t stream) {
    const float* x     = (const float*)d_in[0];
    const float* cw    = (const float*)d_in[1];
    const float* bn_w  = (const float*)d_in[2];
    const float* bn_b  = (const float*)d_in[3];
    const float* bn_m  = (const float*)d_in[4];
    const float* bn_v  = (const float*)d_in[5];
    const float* gamma = (const float*)d_in[6];
    const float* beta  = (const float*)d_in[7];
    float* out = (float*)d_out;

    float* g = (float*)d_ws;                    // NB*NC floats
    float* f = g + NB * NC;                     // NB*KC floats

    gap_kernel<<<NB * NC, 256, 0, stream>>>(x, g);
    filt_kernel<<<dim3(24, NB), 256, 0, stream>>>(g, cw, bn_w, bn_b, bn_m, bn_v, f);
    apply_kernel<<<NB * (NC / CG), 256, 0, stream>>>(x, f, gamma, beta, out);
}